// Round 1
// baseline (974.856 us; speedup 1.0000x reference)
//
#include <hip/hip_runtime.h>
#include <math.h>

// Problem constants: B=1, L=512, C_S=384, H=12, D=32
// ws layout (floats):
//   q_ws    : 512*384            = 196608
//   kv_ws   : 512*768            = 393216
//   o_ws    : 512*384            = 196608
//   bias_ws : 12*512*512         = 3145728   [h][i][j]
//   gate_ws : 12*512*512         = 3145728   [h][i][j] (already sigmoid'ed)
//   wcat_ws : 24*384             = 9216      [h][k] transposed Wb|Wg
// total = 7087104 floats = 28.35 MB

typedef float vf4 __attribute__((ext_vector_type(4)));
typedef __attribute__((address_space(3))) void       lds_vp;
typedef __attribute__((address_space(1))) const void gm_vp;

// ---------------------------------------------------------------------------
// Generic small SGEMM: C[M x N] = A[M x K] @ B[K x N] + bias (row-major).
// Tile 32(M) x 64(N), K-chunk 32, 256 threads, 2x4 micro-tile.
// ---------------------------------------------------------------------------
__global__ __launch_bounds__(256) void sgemm_bias(const float* __restrict__ A, int lda,
                                                  const float* __restrict__ B, int ldb,
                                                  const float* __restrict__ bias,
                                                  float* __restrict__ C, int ldc, int K)
{
    __shared__ float As[32 * 36];   // [k][m]
    __shared__ float Bs[32 * 68];   // [k][n]

    const int t  = threadIdx.x;
    const int m0 = blockIdx.y * 32;
    const int n0 = blockIdx.x * 64;
    const int tx = t & 15;
    const int ty = t >> 4;

    float acc[2][4];
    #pragma unroll
    for (int i = 0; i < 2; ++i)
        #pragma unroll
        for (int j = 0; j < 4; ++j) acc[i][j] = 0.f;

    for (int kc = 0; kc < K; kc += 32) {
        __syncthreads();
        {
            int r = t >> 3, c = (t & 7) * 4;
            float4 av = *(const float4*)&A[(size_t)(m0 + r) * lda + kc + c];
            As[(c + 0) * 36 + r] = av.x;
            As[(c + 1) * 36 + r] = av.y;
            As[(c + 2) * 36 + r] = av.z;
            As[(c + 3) * 36 + r] = av.w;
        }
        #pragma unroll
        for (int i = 0; i < 2; ++i) {
            int slot = i * 256 + t;
            int r = slot >> 4, c = (slot & 15) * 4;
            *(float4*)&Bs[r * 68 + c] = *(const float4*)&B[(size_t)(kc + r) * ldb + n0 + c];
        }
        __syncthreads();
        #pragma unroll 8
        for (int k = 0; k < 32; ++k) {
            float2 a = *(const float2*)&As[k * 36 + ty * 2];
            float4 b = *(const float4*)&Bs[k * 68 + tx * 4];
            acc[0][0] = fmaf(a.x, b.x, acc[0][0]);
            acc[0][1] = fmaf(a.x, b.y, acc[0][1]);
            acc[0][2] = fmaf(a.x, b.z, acc[0][2]);
            acc[0][3] = fmaf(a.x, b.w, acc[0][3]);
            acc[1][0] = fmaf(a.y, b.x, acc[1][0]);
            acc[1][1] = fmaf(a.y, b.y, acc[1][1]);
            acc[1][2] = fmaf(a.y, b.z, acc[1][2]);
            acc[1][3] = fmaf(a.y, b.w, acc[1][3]);
        }
    }

    float4 bv = *(const float4*)&bias[n0 + tx * 4];
    #pragma unroll
    for (int im = 0; im < 2; ++im) {
        float4 r;
        r.x = acc[im][0] + bv.x;
        r.y = acc[im][1] + bv.y;
        r.z = acc[im][2] + bv.z;
        r.w = acc[im][3] + bv.w;
        *(float4*)&C[(size_t)(m0 + ty * 2 + im) * ldc + n0 + tx * 4] = r;
    }
}

// ---------------------------------------------------------------------------
// Tiny prep: wcat[h][k] = (h<12 ? Wb[k][h] : Wg[k][h-12])
// ---------------------------------------------------------------------------
__global__ __launch_bounds__(256) void wcat_kernel(const float* __restrict__ Wb,
                                                   const float* __restrict__ Wg,
                                                   float* __restrict__ wcat)
{
    int idx = blockIdx.x * 256 + threadIdx.x;
    if (idx < 24 * 384) {
        int hh = idx / 384, k = idx % 384;
        wcat[idx] = (hh < 12) ? Wb[k * 12 + hh] : Wg[k * 12 + (hh - 12)];
    }
}

// ---------------------------------------------------------------------------
// bias/gate streaming kernel v5: barrier-free, wave-self-paced.
//
// Why v4 was 250 us (counters: VALUBusy 14.6%, HBM 11%, occ 23.5%): the
// barrier-synced double buffer drained vmcnt(0) every 32-k chunk, and the
// runtime-indexed zt[cur] prevented LDS-DMA alias disambiguation, so the
// compiler serialized loads->compute too. All 8 waves/CU stalled a full
// loaded-system memory round trip per chunk, in lockstep.
//
// Key fact: staging is WAVE-PRIVATE. Wave wv stages rows wv*64..+63 and
// thread t only reads row t (staged by its own wave). So: no barriers at
// all. Two statically-named buffers (compile-time alternation), per-wave
// counted s_waitcnt vmcnt(8) pacing (8 global_load_lds per chunk, depth-2
// pipeline). Waves self-stagger -> HBM always has requests in flight even
// if the compiler adds conservative waits of its own.
//
// LDS stays linear (global_load_lds requires base + lane*16); the bank
// conflict (all 64 lanes hitting banks k4*4..+3 on ds_read_b128, 16-way)
// is fixed by XOR-swizzling the *global source* column with (row&7)*4 and
// reading back with the same XOR: 256 words over 32 banks = conflict-free.
// Accumulation order unchanged -> bitwise-identical output to v4.
// ---------------------------------------------------------------------------
__global__ __launch_bounds__(256) void biasgate_kernel(const float* __restrict__ z,
                                                       const float* __restrict__ wcat,
                                                       const float* __restrict__ bb,
                                                       const float* __restrict__ bg,
                                                       float* __restrict__ bias_out,
                                                       float* __restrict__ gate_out)
{
    __shared__ float bufA[4][64 * 32];   // 32 KB, one 8KB region per wave
    __shared__ float bufB[4][64 * 32];   // 32 KB

    const int t     = threadIdx.x;
    const size_t p0 = (size_t)blockIdx.x * 256;
    const int wv    = t >> 6;            // wave id (uniform per wave)
    const int lane  = t & 63;
    const int lrow  = lane >> 3;         // 0..7   staging row within 8-row group
    const int lcol  = (lane & 7) * 4;    // 0,4,..,28
    const int scol  = lcol ^ (lrow << 2);  // XOR-swizzled source column

    // per-lane global source base; chunk c, group i at  + i*3072 + c*32
    const float* zsrc = z + (p0 + (size_t)(wv * 64 + lrow)) * 384 + scol;
    float* ldsA = &bufA[wv][0];
    float* ldsB = &bufB[wv][0];
    const int r  = lane;                 // compute row within wave region
    const int r7 = t & 7;

    float acc[24];
    #pragma unroll
    for (int h = 0; h < 24; ++h) acc[h] = 0.f;

    // 8 async loads of 1 KB each = one 64x32 chunk for this wave.
    // HW writes lds base + lane*16B = row-linear (lrow*32 + lcol floats). OK.
#define BG_STAGE(LDS, C)                                                    \
    {                                                                       \
        const int kc_ = (C) * 32;                                           \
        _Pragma("unroll")                                                   \
        for (int i = 0; i < 8; ++i)                                         \
            __builtin_amdgcn_global_load_lds(                               \
                (gm_vp*)(zsrc + (size_t)i * 3072 + kc_),                    \
                (lds_vp*)((LDS) + i * 256), 16, 0, 0);                      \
    }

    // LDS[r][c'] holds z[row][kc + (c' ^ ((r&7)*4))]; want cols k4*4..+3
    // -> read at c' = ((k4 ^ r7)*4)..+3 (contiguous, 16B aligned).
    // W reads are wave-uniform -> s_load (scalar cache), free of vmcnt.
#define BG_COMPUTE(LDS, C)                                                  \
    {                                                                       \
        const int kc_ = (C) * 32;                                           \
        _Pragma("unroll")                                                   \
        for (int k4 = 0; k4 < 8; ++k4) {                                    \
            const vf4 zv = *(const vf4*)((LDS) + r * 32 + ((k4 ^ r7) << 2)); \
            const float* wp = wcat + kc_ + k4 * 4;                          \
            _Pragma("unroll")                                               \
            for (int hh = 0; hh < 24; ++hh) {                               \
                float4 w = *(const float4*)&wp[hh * 384];                   \
                acc[hh] = fmaf(zv.x, w.x, fmaf(zv.y, w.y,                   \
                          fmaf(zv.z, w.z, fmaf(zv.w, w.w, acc[hh]))));      \
            }                                                               \
        }                                                                   \
    }

    // Only vmem ops in flight are our global_load_lds (weights are s_load,
    // outputs come after the final drain) -> counted waits are exact.
#define BG_WAIT8 asm volatile("s_waitcnt vmcnt(8)" ::: "memory")
#define BG_WAIT0 asm volatile("s_waitcnt vmcnt(0)" ::: "memory")

    BG_STAGE(ldsA, 0);
    BG_STAGE(ldsB, 1);

    #pragma unroll 1
    for (int c = 0; c < 12; c += 2) {
        BG_WAIT8;                 // oldest 8 (chunk c into A) retired
        BG_COMPUTE(ldsA, c);
        // reuse-after-read is safe wave-locally: DMA write lands a full
        // memory round trip after issue; ds_reads above retire at issue.
        // At c==10 restage chunk 10 (just read -> L2-hot) purely to keep
        // the vmcnt counting uniform; drained by the final WAIT0.
        BG_STAGE(ldsA, (c + 2 < 12) ? c + 2 : c);
        BG_WAIT8;                 // chunk c+1 (into B) retired
        BG_COMPUTE(ldsB, c + 1);
        if (c + 3 < 12) BG_STAGE(ldsB, c + 3);
    }
    BG_WAIT0;                     // drain dummy before LDS dealloc / stores

    #pragma unroll
    for (int hh = 0; hh < 12; ++hh)
        bias_out[(size_t)hh * 262144 + p0 + t] = acc[hh] + bb[hh];
    #pragma unroll
    for (int hh = 0; hh < 12; ++hh) {
        float x = acc[12 + hh] + bg[hh];
        gate_out[(size_t)hh * 262144 + p0 + t] = 1.f / (1.f + expf(-x));
    }
#undef BG_STAGE
#undef BG_COMPUTE
#undef BG_WAIT8
#undef BG_WAIT0
}

// ---------------------------------------------------------------------------
// Attention (R2 known-good): block = (h, 16 query rows). Full 16x512 logits
// tile in LDS. A: logits  B: softmax*gate  C: o = attn @ v.
// ---------------------------------------------------------------------------
__global__ __launch_bounds__(256) void attn_kernel(const float* __restrict__ q_ws,
                                                   const float* __restrict__ kv_ws,
                                                   const float* __restrict__ bias_ws,
                                                   const float* __restrict__ gate_ws,
                                                   const int* __restrict__ mask,
                                                   float* __restrict__ o_ws)
{
    __shared__ float ql[16 * 36];
    __shared__ float kl[128 * 36];
    __shared__ float att[16 * 516];   // row stride 516 (pad 4)
    __shared__ int   mint[16];

    const int t  = threadIdx.x;
    const int h  = blockIdx.y;
    const int i0 = blockIdx.x * 16;

    for (int idx = t; idx < 512; idx += 256) {
        int ii = idx >> 5, d = idx & 31;
        ql[ii * 36 + d] = q_ws[(size_t)(i0 + ii) * 384 + h * 32 + d];
    }
    if (t < 16) mint[t] = mask[i0 + t];

    const float inv = 0.17677669529663687f;   // 1/sqrt(32)
    const int jl = t & 127;
    const int ip = t >> 7;                     // 0 or 1

    // Phase A: logits
    for (int jc = 0; jc < 4; ++jc) {
        const int j0 = jc * 128;
        __syncthreads();
        for (int idx = t; idx < 4096; idx += 256) {
            int jj = idx >> 5, d = idx & 31;
            kl[jj * 36 + d] = kv_ws[(size_t)(j0 + jj) * 768 + h * 32 + d];
        }
        __syncthreads();
        float4 kr[8];
        #pragma unroll
        for (int x = 0; x < 8; ++x) kr[x] = *(const float4*)&kl[jl * 36 + x * 4];
        const int mj = mask[j0 + jl];
        #pragma unroll
        for (int rr = 0; rr < 8; ++rr) {
            int ii = ip + rr * 2;
            float dot = 0.f;
            #pragma unroll
            for (int x = 0; x < 8; ++x) {
                float4 qv = *(const float4*)&ql[ii * 36 + x * 4];
                dot = fmaf(kr[x].x, qv.x, dot);
                dot = fmaf(kr[x].y, qv.y, dot);
                dot = fmaf(kr[x].z, qv.z, dot);
                dot = fmaf(kr[x].w, qv.w, dot);
            }
            float bv = bias_ws[((size_t)h << 18) + (size_t)(i0 + ii) * 512 + j0 + jl];
            float lg = fmaf(dot, inv, bv);
            att[ii * 516 + j0 + jl] = (mint[ii] != 0 && mj != 0) ? lg : -1e9f;
        }
    }
    __syncthreads();

    // Phase B: softmax * gate (row = t/16, 16 lanes per row, 32 elems each)
    {
        const int rr = t >> 4, g = t & 15;
        const int base = rr * 516 + g;
        float mx = -3.0e38f;
        #pragma unroll
        for (int n = 0; n < 32; ++n) mx = fmaxf(mx, att[base + n * 16]);
        #pragma unroll
        for (int off = 8; off >= 1; off >>= 1) mx = fmaxf(mx, __shfl_xor(mx, off));
        float sum = 0.f;
        #pragma unroll
        for (int n = 0; n < 32; ++n) {
            float e = expf(att[base + n * 16] - mx);
            att[base + n * 16] = e;
            sum += e;
        }
        #pragma unroll
        for (int off = 8; off >= 1; off >>= 1) sum += __shfl_xor(sum, off);
        float isum = 1.f / sum;
        const size_t gbase = ((size_t)h << 18) + (size_t)(i0 + rr) * 512 + g;
        #pragma unroll
        for (int n = 0; n < 32; ++n) {
            float gt = gate_ws[gbase + n * 16];
            att[base + n * 16] *= isum * gt;
        }
    }
    __syncthreads();

    // Phase C: o = attn @ v. thread = (group g = rows {g, g+8}, d)
    {
        const int d = t & 31, grp = t >> 5;
        const float* vp = kv_ws + 384 + h * 32 + d;
        float a0 = 0.f, a1 = 0.f;
        #pragma unroll 8
        for (int j = 0; j < 512; ++j) {
            float vv = vp[(size_t)j * 768];
            a0 = fmaf(att[grp * 516 + j], vv, a0);
            a1 = fmaf(att[(grp + 8) * 516 + j], vv, a1);
        }
        o_ws[(size_t)(i0 + grp) * 384 + h * 32 + d]     = a0;
        o_ws[(size_t)(i0 + grp + 8) * 384 + h * 32 + d] = a1;
    }
}

// ---------------------------------------------------------------------------
extern "C" void kernel_launch(void* const* d_in, const int* in_sizes, int n_in,
                              void* d_out, int out_size, void* d_ws, size_t ws_size,
                              hipStream_t stream)
{
    const float* s    = (const float*)d_in[0];
    const float* z    = (const float*)d_in[1];
    const int*   mask = (const int*)  d_in[2];
    const float* Wq   = (const float*)d_in[3];
    const float* bq   = (const float*)d_in[4];
    const float* Wkv  = (const float*)d_in[5];
    const float* bkv  = (const float*)d_in[6];
    const float* Wb   = (const float*)d_in[7];
    const float* bb   = (const float*)d_in[8];
    const float* Wg   = (const float*)d_in[9];
    const float* bg   = (const float*)d_in[10];
    const float* Wout = (const float*)d_in[11];
    const float* bout = (const float*)d_in[12];
    float* out = (float*)d_out;

    float* ws      = (float*)d_ws;
    float* q_ws    = ws;                          // 512*384
    float* kv_ws   = q_ws + 512 * 384;            // 512*768
    float* o_ws    = kv_ws + 512 * 768;           // 512*384
    float* bias_ws = o_ws + 512 * 384;            // 12*512*512
    float* gate_ws = bias_ws + 12 * 512 * 512;    // 12*512*512
    float* wcat_ws = gate_ws + 12 * 512 * 512;    // 24*384

    // W transpose prep (tiny)
    wcat_kernel<<<36, 256, 0, stream>>>(Wb, Wg, wcat_ws);
    // q = s @ Wq + bq
    sgemm_bias<<<dim3(384 / 64, 512 / 32), 256, 0, stream>>>(s, 384, Wq, 384, bq, q_ws, 384, 384);
    // kv = s @ Wkv + bkv
    sgemm_bias<<<dim3(768 / 64, 512 / 32), 256, 0, stream>>>(s, 384, Wkv, 768, bkv, kv_ws, 768, 384);
    // bias/gate = z @ [Wb|Wg]    (the 402 MB stream)
    biasgate_kernel<<<1024, 256, 0, stream>>>(z, wcat_ws, bb, bg, bias_ws, gate_ws);
    // softmax(qk/sqrt(D) + bias, mask) * gate, then @ v
    attn_kernel<<<dim3(512 / 16, 12), 256, 0, stream>>>(q_ws, kv_ws, bias_ws, gate_ws, mask, o_ws);
    // out = o @ Wout + bout
    sgemm_bias<<<dim3(384 / 64, 512 / 32), 256, 0, stream>>>(o_ws, 384, Wout, 384, bout, out, 384, 384);
}

// Round 2
// 720.393 us; speedup vs baseline: 1.3532x; 1.3532x over previous
//
#include <hip/hip_runtime.h>
#include <math.h>

// Problem constants: B=1, L=512, C_S=384, H=12, D=32
// ws layout (floats):
//   q_ws    : 512*384            = 196608
//   kv_ws   : 512*768            = 393216
//   o_ws    : 512*384            = 196608
//   bias_ws : 12*512*512         = 3145728   [h][i][j]
//   gate_ws : 12*512*512         = 3145728   [h][i][j] (already sigmoid'ed)
//   wcat_ws : 24*384             = 9216      [h][k] transposed Wb|Wg
// total = 7087104 floats = 28.35 MB

typedef float vf4 __attribute__((ext_vector_type(4)));
typedef __attribute__((address_space(3))) void       lds_vp;
typedef __attribute__((address_space(1))) const void gm_vp;

// ---------------------------------------------------------------------------
// Generic small SGEMM: C[M x N] = A[M x K] @ B[K x N] + bias (row-major).
// Tile 32(M) x 64(N), K-chunk 32, 256 threads, 2x4 micro-tile.
// ---------------------------------------------------------------------------
__global__ __launch_bounds__(256) void sgemm_bias(const float* __restrict__ A, int lda,
                                                  const float* __restrict__ B, int ldb,
                                                  const float* __restrict__ bias,
                                                  float* __restrict__ C, int ldc, int K)
{
    __shared__ float As[32 * 36];   // [k][m]
    __shared__ float Bs[32 * 68];   // [k][n]

    const int t  = threadIdx.x;
    const int m0 = blockIdx.y * 32;
    const int n0 = blockIdx.x * 64;
    const int tx = t & 15;
    const int ty = t >> 4;

    float acc[2][4];
    #pragma unroll
    for (int i = 0; i < 2; ++i)
        #pragma unroll
        for (int j = 0; j < 4; ++j) acc[i][j] = 0.f;

    for (int kc = 0; kc < K; kc += 32) {
        __syncthreads();
        {
            int r = t >> 3, c = (t & 7) * 4;
            float4 av = *(const float4*)&A[(size_t)(m0 + r) * lda + kc + c];
            As[(c + 0) * 36 + r] = av.x;
            As[(c + 1) * 36 + r] = av.y;
            As[(c + 2) * 36 + r] = av.z;
            As[(c + 3) * 36 + r] = av.w;
        }
        #pragma unroll
        for (int i = 0; i < 2; ++i) {
            int slot = i * 256 + t;
            int r = slot >> 4, c = (slot & 15) * 4;
            *(float4*)&Bs[r * 68 + c] = *(const float4*)&B[(size_t)(kc + r) * ldb + n0 + c];
        }
        __syncthreads();
        #pragma unroll 8
        for (int k = 0; k < 32; ++k) {
            float2 a = *(const float2*)&As[k * 36 + ty * 2];
            float4 b = *(const float4*)&Bs[k * 68 + tx * 4];
            acc[0][0] = fmaf(a.x, b.x, acc[0][0]);
            acc[0][1] = fmaf(a.x, b.y, acc[0][1]);
            acc[0][2] = fmaf(a.x, b.z, acc[0][2]);
            acc[0][3] = fmaf(a.x, b.w, acc[0][3]);
            acc[1][0] = fmaf(a.y, b.x, acc[1][0]);
            acc[1][1] = fmaf(a.y, b.y, acc[1][1]);
            acc[1][2] = fmaf(a.y, b.z, acc[1][2]);
            acc[1][3] = fmaf(a.y, b.w, acc[1][3]);
        }
    }

    float4 bv = *(const float4*)&bias[n0 + tx * 4];
    #pragma unroll
    for (int im = 0; im < 2; ++im) {
        float4 r;
        r.x = acc[im][0] + bv.x;
        r.y = acc[im][1] + bv.y;
        r.z = acc[im][2] + bv.z;
        r.w = acc[im][3] + bv.w;
        *(float4*)&C[(size_t)(m0 + ty * 2 + im) * ldc + n0 + tx * 4] = r;
    }
}

// ---------------------------------------------------------------------------
// Tiny prep: wcat[h][k] = (h<12 ? Wb[k][h] : Wg[k][h-12])
// ---------------------------------------------------------------------------
__global__ __launch_bounds__(256) void wcat_kernel(const float* __restrict__ Wb,
                                                   const float* __restrict__ Wg,
                                                   float* __restrict__ wcat)
{
    int idx = blockIdx.x * 256 + threadIdx.x;
    if (idx < 24 * 384) {
        int hh = idx / 384, k = idx % 384;
        wcat[idx] = (hh < 12) ? Wb[k * 12 + hh] : Wg[k * 12 + (hh - 12)];
    }
}

// ---------------------------------------------------------------------------
// bias/gate streaming kernel v6: v4 barrier structure + occupancy fix.
//
// History: v4 (barrier dbuf, 32-col chunks, 64KB LDS) = 250 us at 11% HBM,
// occ 23.5% (2 blocks/CU = 2 barrier domains; every chunk the whole block
// drains vmcnt(0) with nothing to hide under). v5 (barrier-free, inline-asm
// counted vmcnt + "memory" clobbers) = 523 us: the clobbers killed s_load
// weight caching / address hoisting (VALUBusy 15->30%) and collapsed the
// pipeline. REVERTED.
//
// v6: keep the known-good barrier-synced double buffer, but chunk = 16
// k-columns -> LDS 32 KB -> 5 blocks/CU (all 1024 blocks co-resident,
// 20 waves/CU). Five independently-phased barrier domains per CU: one
// block's vmcnt(0) drain hides under the other four blocks' FMAs (the m97
// mechanism). Statically-named buffer alternation (2x-unrolled loop) so
// LDS-DMA alias analysis sees distinct objects. No inline asm.
//
// Bank conflicts (the one v5 piece that worked, adapted to 16-col rows):
// LDS stays row-linear (global_load_lds writes base + lane*16B), but the
// GLOBAL source column is XOR-swizzled per row: row r quad q' holds source
// quad q' ^ s(r), s(r) = (r>>1)&3. Read back at quad k4 ^ s(r). For a
// wave's b128 read of rows 0..63 at fixed k4, 8 consecutive lanes then
// cover all 32 banks exactly once -> conflict-free (was 8-way).
// Accumulation order unchanged -> bitwise-identical to v4.
// ---------------------------------------------------------------------------
__global__ __launch_bounds__(256) void biasgate_kernel(const float* __restrict__ z,
                                                       const float* __restrict__ wcat,
                                                       const float* __restrict__ bb,
                                                       const float* __restrict__ bg,
                                                       float* __restrict__ bias_out,
                                                       float* __restrict__ gate_out)
{
    __shared__ float ztA[256 * 16];   // 16 KB
    __shared__ float ztB[256 * 16];   // 16 KB

    const int t     = threadIdx.x;
    const size_t p0 = (size_t)blockIdx.x * 256;
    const int wv    = t >> 6;             // wave id (uniform per wave)
    const int lane  = t & 63;
    // staging: load i covers rows wv*64 + i*16 + (lane>>2); lane quad = lane&3
    const int lrow  = lane >> 2;          // 0..15
    const int lq    = lane & 3;           // LDS quad this lane fills
    const int sq    = lq ^ ((lane >> 3) & 3);   // swizzled SOURCE quad
    const int scol  = sq << 2;            // source col offset 0,4,8,12

    const float* zsrc = z + (p0 + (size_t)(wv * 64 + lrow)) * 384 + scol;
    const int st = (t >> 1) & 3;          // read-side swizzle s(r) for row r=t

    float acc[24];
    #pragma unroll
    for (int h = 0; h < 24; ++h) acc[h] = 0.f;

    // 4 async 1KB loads = one 256-row x 16-col chunk (load i: 16 rows).
    // LDS dest is wave-uniform base; HW writes lane*16B = row-linear.
#define BG_STAGE(LDS, C)                                                    \
    {                                                                       \
        const int kc_ = (C) * 16;                                           \
        _Pragma("unroll")                                                   \
        for (int i = 0; i < 4; ++i)                                         \
            __builtin_amdgcn_global_load_lds(                               \
                (gm_vp*)(zsrc + (size_t)(i * 16) * 384 + kc_),              \
                (lds_vp*)(&(LDS)[(wv * 64 + i * 16) * 16]), 16, 0, 0);      \
    }

    // LDS[r][q'] = z[row r][kc + 4*(q'^s(r))]; source quad k4 lives at
    // q' = k4 ^ s(r) (contiguous 16B, aligned). Weights wave-uniform -> s_load.
#define BG_COMPUTE(LDS, C)                                                  \
    {                                                                       \
        const int kc_ = (C) * 16;                                           \
        _Pragma("unroll")                                                   \
        for (int k4 = 0; k4 < 4; ++k4) {                                    \
            const vf4 zv = *(const vf4*)&(LDS)[t * 16 + ((k4 ^ st) << 2)];  \
            const float* wp = wcat + kc_ + k4 * 4;                          \
            _Pragma("unroll")                                               \
            for (int hh = 0; hh < 24; ++hh) {                               \
                float4 w = *(const float4*)&wp[hh * 384];                   \
                acc[hh] = fmaf(zv.x, w.x, fmaf(zv.y, w.y,                   \
                          fmaf(zv.z, w.z, fmaf(zv.w, w.w, acc[hh]))));      \
            }                                                               \
        }                                                                   \
    }

    BG_STAGE(ztA, 0);
    __syncthreads();   // chunk 0 resident

    // 24 chunks of 16 cols; 2x unrolled so buffer names are compile-time.
    // Pattern per half-iter: issue next chunk's loads, compute current from
    // LDS, barrier (drains the in-flight loads AFTER compute has run).
    #pragma unroll 1
    for (int c = 0; c < 24; c += 2) {
        BG_STAGE(ztB, c + 1);
        BG_COMPUTE(ztA, c);
        __syncthreads();
        if (c + 2 < 24) BG_STAGE(ztA, c + 2);
        BG_COMPUTE(ztB, c + 1);
        __syncthreads();
    }

    #pragma unroll
    for (int hh = 0; hh < 12; ++hh)
        bias_out[(size_t)hh * 262144 + p0 + t] = acc[hh] + bb[hh];
    #pragma unroll
    for (int hh = 0; hh < 12; ++hh) {
        float x = acc[12 + hh] + bg[hh];
        gate_out[(size_t)hh * 262144 + p0 + t] = 1.f / (1.f + expf(-x));
    }
#undef BG_STAGE
#undef BG_COMPUTE
}

// ---------------------------------------------------------------------------
// Attention (R2 known-good): block = (h, 16 query rows). Full 16x512 logits
// tile in LDS. A: logits  B: softmax*gate  C: o = attn @ v.
// ---------------------------------------------------------------------------
__global__ __launch_bounds__(256) void attn_kernel(const float* __restrict__ q_ws,
                                                   const float* __restrict__ kv_ws,
                                                   const float* __restrict__ bias_ws,
                                                   const float* __restrict__ gate_ws,
                                                   const int* __restrict__ mask,
                                                   float* __restrict__ o_ws)
{
    __shared__ float ql[16 * 36];
    __shared__ float kl[128 * 36];
    __shared__ float att[16 * 516];   // row stride 516 (pad 4)
    __shared__ int   mint[16];

    const int t  = threadIdx.x;
    const int h  = blockIdx.y;
    const int i0 = blockIdx.x * 16;

    for (int idx = t; idx < 512; idx += 256) {
        int ii = idx >> 5, d = idx & 31;
        ql[ii * 36 + d] = q_ws[(size_t)(i0 + ii) * 384 + h * 32 + d];
    }
    if (t < 16) mint[t] = mask[i0 + t];

    const float inv = 0.17677669529663687f;   // 1/sqrt(32)
    const int jl = t & 127;
    const int ip = t >> 7;                     // 0 or 1

    // Phase A: logits
    for (int jc = 0; jc < 4; ++jc) {
        const int j0 = jc * 128;
        __syncthreads();
        for (int idx = t; idx < 4096; idx += 256) {
            int jj = idx >> 5, d = idx & 31;
            kl[jj * 36 + d] = kv_ws[(size_t)(j0 + jj) * 768 + h * 32 + d];
        }
        __syncthreads();
        float4 kr[8];
        #pragma unroll
        for (int x = 0; x < 8; ++x) kr[x] = *(const float4*)&kl[jl * 36 + x * 4];
        const int mj = mask[j0 + jl];
        #pragma unroll
        for (int rr = 0; rr < 8; ++rr) {
            int ii = ip + rr * 2;
            float dot = 0.f;
            #pragma unroll
            for (int x = 0; x < 8; ++x) {
                float4 qv = *(const float4*)&ql[ii * 36 + x * 4];
                dot = fmaf(kr[x].x, qv.x, dot);
                dot = fmaf(kr[x].y, qv.y, dot);
                dot = fmaf(kr[x].z, qv.z, dot);
                dot = fmaf(kr[x].w, qv.w, dot);
            }
            float bv = bias_ws[((size_t)h << 18) + (size_t)(i0 + ii) * 512 + j0 + jl];
            float lg = fmaf(dot, inv, bv);
            att[ii * 516 + j0 + jl] = (mint[ii] != 0 && mj != 0) ? lg : -1e9f;
        }
    }
    __syncthreads();

    // Phase B: softmax * gate (row = t/16, 16 lanes per row, 32 elems each)
    {
        const int rr = t >> 4, g = t & 15;
        const int base = rr * 516 + g;
        float mx = -3.0e38f;
        #pragma unroll
        for (int n = 0; n < 32; ++n) mx = fmaxf(mx, att[base + n * 16]);
        #pragma unroll
        for (int off = 8; off >= 1; off >>= 1) mx = fmaxf(mx, __shfl_xor(mx, off));
        float sum = 0.f;
        #pragma unroll
        for (int n = 0; n < 32; ++n) {
            float e = expf(att[base + n * 16] - mx);
            att[base + n * 16] = e;
            sum += e;
        }
        #pragma unroll
        for (int off = 8; off >= 1; off >>= 1) sum += __shfl_xor(sum, off);
        float isum = 1.f / sum;
        const size_t gbase = ((size_t)h << 18) + (size_t)(i0 + rr) * 512 + g;
        #pragma unroll
        for (int n = 0; n < 32; ++n) {
            float gt = gate_ws[gbase + n * 16];
            att[base + n * 16] *= isum * gt;
        }
    }
    __syncthreads();

    // Phase C: o = attn @ v. thread = (group g = rows {g, g+8}, d)
    {
        const int d = t & 31, grp = t >> 5;
        const float* vp = kv_ws + 384 + h * 32 + d;
        float a0 = 0.f, a1 = 0.f;
        #pragma unroll 8
        for (int j = 0; j < 512; ++j) {
            float vv = vp[(size_t)j * 768];
            a0 = fmaf(att[grp * 516 + j], vv, a0);
            a1 = fmaf(att[(grp + 8) * 516 + j], vv, a1);
        }
        o_ws[(size_t)(i0 + grp) * 384 + h * 32 + d]     = a0;
        o_ws[(size_t)(i0 + grp + 8) * 384 + h * 32 + d] = a1;
    }
}

// ---------------------------------------------------------------------------
extern "C" void kernel_launch(void* const* d_in, const int* in_sizes, int n_in,
                              void* d_out, int out_size, void* d_ws, size_t ws_size,
                              hipStream_t stream)
{
    const float* s    = (const float*)d_in[0];
    const float* z    = (const float*)d_in[1];
    const int*   mask = (const int*)  d_in[2];
    const float* Wq   = (const float*)d_in[3];
    const float* bq   = (const float*)d_in[4];
    const float* Wkv  = (const float*)d_in[5];
    const float* bkv  = (const float*)d_in[6];
    const float* Wb   = (const float*)d_in[7];
    const float* bb   = (const float*)d_in[8];
    const float* Wg   = (const float*)d_in[9];
    const float* bg   = (const float*)d_in[10];
    const float* Wout = (const float*)d_in[11];
    const float* bout = (const float*)d_in[12];
    float* out = (float*)d_out;

    float* ws      = (float*)d_ws;
    float* q_ws    = ws;                          // 512*384
    float* kv_ws   = q_ws + 512 * 384;            // 512*768
    float* o_ws    = kv_ws + 512 * 768;           // 512*384
    float* bias_ws = o_ws + 512 * 384;            // 12*512*512
    float* gate_ws = bias_ws + 12 * 512 * 512;    // 12*512*512
    float* wcat_ws = gate_ws + 12 * 512 * 512;    // 24*384

    // W transpose prep (tiny)
    wcat_kernel<<<36, 256, 0, stream>>>(Wb, Wg, wcat_ws);
    // q = s @ Wq + bq
    sgemm_bias<<<dim3(384 / 64, 512 / 32), 256, 0, stream>>>(s, 384, Wq, 384, bq, q_ws, 384, 384);
    // kv = s @ Wkv + bkv
    sgemm_bias<<<dim3(768 / 64, 512 / 32), 256, 0, stream>>>(s, 384, Wkv, 768, bkv, kv_ws, 768, 384);
    // bias/gate = z @ [Wb|Wg]    (the 402 MB stream)
    biasgate_kernel<<<1024, 256, 0, stream>>>(z, wcat_ws, bb, bg, bias_ws, gate_ws);
    // softmax(qk/sqrt(D) + bias, mask) * gate, then @ v
    attn_kernel<<<dim3(512 / 16, 12), 256, 0, stream>>>(q_ws, kv_ws, bias_ws, gate_ws, mask, o_ws);
    // out = o @ Wout + bout
    sgemm_bias<<<dim3(384 / 64, 512 / 32), 256, 0, stream>>>(o_ws, 384, Wout, 384, bout, out, 384, 384);
}